// Round 1
// baseline (2783.008 us; speedup 1.0000x reference)
//
#include <hip/hip_runtime.h>
#include <hip/hip_bf16.h>
#include <cstdint>
#include <cstddef>

// ---------------------------------------------------------------------------
// When2commFusion on MI355X.
// Pipeline: scatter+affine-warp -> 5x conv3x3/BN/ReLU (fp16 hi/lo split MFMA,
// fp32 accum) -> key/query MLPs (fp32) -> sparsemax -> weighted re-warp fusion.
// Workspace requirement: ~470 MiB (activations stored as padded-NHWC fp16
// hi/lo planes; fusion re-samples x instead of keeping fp32 warped).
// ---------------------------------------------------------------------------

typedef _Float16 half8 __attribute__((ext_vector_type(8)));
typedef float f32x4 __attribute__((ext_vector_type(4)));

#define B_ 4
#define L_ 5
#define C_ 256
#define H_ 64
#define W_ 256
#define NS 20

__device__ __forceinline__ void splitf(float v, _Float16& h, _Float16& l) {
  _Float16 hh = (_Float16)v;
  h = hh;
  l = (_Float16)(v - (float)hh);
}

// ---------------------------------------------------------------------------
// Weight prep: fold BN scale, transpose to [tap][oc][ic], split fp16 hi/lo.
// ---------------------------------------------------------------------------
__global__ __launch_bounds__(256) void prep_w_kernel(
    const float* __restrict__ w1, const float* __restrict__ s1,
    const float* __restrict__ w2, const float* __restrict__ s2,
    const float* __restrict__ w3, const float* __restrict__ s3,
    const float* __restrict__ w4, const float* __restrict__ s4,
    const float* __restrict__ w5, const float* __restrict__ s5,
    _Float16* __restrict__ o1, _Float16* __restrict__ o2,
    _Float16* __restrict__ o3, _Float16* __restrict__ o4,
    _Float16* __restrict__ o5)
{
  const int sz[5]   = {73728, 9216, 18432, 36864, 73728};
  const int cin[5]  = {256, 32, 32, 64, 64};
  const int cout[5] = {32, 32, 64, 64, 128};
  const float* wp[5] = {w1, w2, w3, w4, w5};
  const float* sp[5] = {s1, s2, s3, s4, s5};
  _Float16* op[5] = {o1, o2, o3, o4, o5};

  int e = blockIdx.x * 256 + threadIdx.x;
  if (e >= 211968) return;
  int lay = 0, base = 0;
  while (lay < 4 && e >= base + sz[lay]) { base += sz[lay]; ++lay; }
  int local = e - base;
  int CIN = cin[lay], COUT = cout[lay];
  int oc = local / (CIN * 9);
  int ic = (local / 9) % CIN;
  int t  = local % 9;
  float v = wp[lay][local] * sp[lay][oc];
  _Float16 h, lo; splitf(v, h, lo);
  int planeS = 9 * COUT * CIN;
  int dst = (t * COUT + oc) * CIN + ic;
  op[lay][dst] = h;
  op[lay][planeS + dst] = lo;
}

// ---------------------------------------------------------------------------
// Zero the 1-px padding border of a padded-NHWC activation buffer (2 planes).
// unit = 8 halfs.
// ---------------------------------------------------------------------------
__global__ __launch_bounds__(256) void zero_border_kernel(
    _Float16* __restrict__ act, int H2, int W2, int C, size_t planeStride)
{
  long u = (long)blockIdx.x * 256 + threadIdx.x;
  int borderPx = 2 * W2 + 2 * (H2 - 2);
  int c8n = C >> 3;
  long total = (long)borderPx * c8n * NS * 2;
  if (u >= total) return;
  int c8 = (int)(u % c8n); long t = u / c8n;
  int bp = (int)(t % borderPx); t /= borderPx;
  int n = (int)(t % NS); int pl = (int)(t / NS);
  int yy, xx;
  if (bp < 2 * W2) { yy = (bp < W2) ? 0 : (H2 - 1); xx = bp % W2; }
  else { int j = bp - 2 * W2; xx = (j & 1) ? (W2 - 1) : 0; yy = 1 + (j >> 1); }
  size_t addr = (size_t)pl * planeStride + (size_t)n * ((size_t)H2 * W2 * C)
              + ((size_t)yy * W2 + xx) * C + (size_t)c8 * 8;
  half8 z = {};
  *(half8*)(act + addr) = z;
}

// ---------------------------------------------------------------------------
// Scatter + affine warp + fp16 split, writing conv1 input (padded NHWC hi/lo).
// Block = (y row, slot n); 256 threads = x.
// ---------------------------------------------------------------------------
__global__ __launch_bounds__(256) void warp_split_kernel(
    const float* __restrict__ xin, const int* __restrict__ rec,
    const float* __restrict__ ptm, _Float16* __restrict__ act0)
{
  const int y = blockIdx.x;
  const int n = blockIdx.y;
  const int x = threadIdx.x;
  const int b = n / L_, l = n % L_;
  int offs = 0;
  #pragma unroll
  for (int i = 0; i < 4; ++i) offs += (i < b) ? rec[i] : 0;
  const bool valid = l < rec[b];
  const int src = offs + l;

  __shared__ float tile[256][33];

  const float* M = ptm + ((size_t)b * 25 + l) * 6;
  float gx = (2.f * x + 1.f) / W_ - 1.f;
  float gy = (2.f * y + 1.f) / H_ - 1.f;
  float c0 = M[0] * gx + M[1] * gy + M[2];
  float c1 = M[3] * gx + M[4] * gy + M[5];
  float ix = ((c0 + 1.f) * W_ - 1.f) * 0.5f;
  float iy = ((c1 + 1.f) * H_ - 1.f) * 0.5f;
  float x0f = floorf(ix), y0f = floorf(iy);
  float wx = ix - x0f, wy = iy - y0f;
  bool vx0 = (x0f >= 0.f) && (x0f <= (float)(W_ - 1));
  bool vx1 = (x0f + 1.f >= 0.f) && (x0f + 1.f <= (float)(W_ - 1));
  bool vy0 = (y0f >= 0.f) && (y0f <= (float)(H_ - 1));
  bool vy1 = (y0f + 1.f >= 0.f) && (y0f + 1.f <= (float)(H_ - 1));
  int xi0 = min(max((int)x0f, 0), W_ - 1);
  int xi1 = min(max((int)x0f + 1, 0), W_ - 1);
  int yi0 = min(max((int)y0f, 0), H_ - 1);
  int yi1 = min(max((int)y0f + 1, 0), H_ - 1);
  float a00 = (vx0 && vy0) ? (1.f - wy) * (1.f - wx) : 0.f;
  float a01 = (vx1 && vy0) ? (1.f - wy) * wx : 0.f;
  float a10 = (vx0 && vy1) ? wy * (1.f - wx) : 0.f;
  float a11 = (vx1 && vy1) ? wy * wx : 0.f;
  int o00 = yi0 * W_ + xi0, o01 = yi0 * W_ + xi1;
  int o10 = yi1 * W_ + xi0, o11 = yi1 * W_ + xi1;
  const float* sb = xin + (size_t)src * (C_ * H_ * W_);

  const size_t SS0 = (size_t)66 * 258 * 256;
  const size_t PS0 = SS0 * NS;

  for (int cc = 0; cc < 8; ++cc) {
    __syncthreads();
    #pragma unroll 4
    for (int ci = 0; ci < 32; ++ci) {
      int c = cc * 32 + ci;
      float v = 0.f;
      if (valid) {
        const float* p = sb + (size_t)c * (H_ * W_);
        v = a00 * p[o00] + a01 * p[o01] + a10 * p[o10] + a11 * p[o11];
      }
      tile[x][ci] = v;
    }
    __syncthreads();
    for (int u = threadIdx.x; u < 8192; u += 256) {
      int px = u >> 5, ci = u & 31;
      float v = tile[px][ci];
      _Float16 h, lo; splitf(v, h, lo);
      size_t addr = (size_t)n * SS0 + ((size_t)(y + 1) * 258 + (px + 1)) * 256
                  + cc * 32 + ci;
      act0[addr] = h;
      act0[PS0 + addr] = lo;
    }
  }
}

// ---------------------------------------------------------------------------
// Implicit-GEMM conv3x3 + BN bias + ReLU, fp16 hi/lo split, 16x16x32 MFMA.
// Block = 256 thr (4 waves, each 32m x 32n). M-tile = BM output px of one row.
// ---------------------------------------------------------------------------
template<int CIN, int COUT, int HIN, int WIN, int STRIDE, int BM, int BN,
         int WC, int LAST>
__global__ __launch_bounds__(256, 2) void conv_kernel(
    const _Float16* __restrict__ ain, const _Float16* __restrict__ wsp,
    const float* __restrict__ bias, _Float16* __restrict__ aout,
    float* __restrict__ fout)
{
  constexpr int H2 = HIN + 2, W2 = WIN + 2;
  constexpr int HOUT = HIN / STRIDE, WOUT = WIN / STRIDE;
  constexpr int XT = WOUT / BM;
  constexpr int WS = (STRIDE == 1) ? (BM + 2) : (2 * BM + 2);
  constexpr int KC = CIN / 32;
  constexpr long SS_IN = (long)H2 * W2 * CIN;
  constexpr long PS_IN = (long)NS * SS_IN;
  constexpr int H2O = HOUT + 2, W2O = WOUT + 2;
  constexpr long SS_OUT = (long)H2O * W2O * COUT;
  constexpr long PS_OUT = (long)NS * SS_OUT;
  constexpr int WPLANE = 9 * COUT * CIN;

  __shared__ _Float16 sa[2][3][WS][40];

  const int mb = blockIdx.x;
  const int y = mb / XT;
  const int x0 = (mb % XT) * BM;
  const int n0 = blockIdx.y * BN;
  const int n = blockIdx.z;
  const int tid = threadIdx.x;
  const int lane = tid & 63;
  const int wv = tid >> 6;
  const int mo = 32 * (wv / WC);
  const int no = 32 * (wv % WC);
  const int l15 = lane & 15, l4 = lane >> 4;

  f32x4 acc[2][2] = {};
  const _Float16* inb = ain + (long)n * SS_IN;

  for (int kc = 0; kc < KC; ++kc) {
    __syncthreads();
    {
      const int units = 3 * WS * 4;
      #pragma unroll
      for (int pl = 0; pl < 2; ++pl) {
        const _Float16* src_base = inb + (long)pl * PS_IN + kc * 32;
        for (int u = tid; u < units; u += 256) {
          int ky = u / (WS * 4);
          int r = u - ky * (WS * 4);
          int px = r >> 2, c8 = r & 3;
          int gy = y * STRIDE + ky;
          int gx = x0 * STRIDE + px;
          const _Float16* spp = src_base + ((long)gy * W2 + gx) * CIN + c8 * 8;
          *(half8*)(&sa[pl][ky][px][c8 * 8]) = *(const half8*)spp;
        }
      }
    }
    __syncthreads();
    #pragma unroll
    for (int ky = 0; ky < 3; ++ky) {
      #pragma unroll
      for (int kx = 0; kx < 3; ++kx) {
        half8 ah[2], al[2];
        #pragma unroll
        for (int mt = 0; mt < 2; ++mt) {
          int px = (mo + 16 * mt + l15) * STRIDE + kx;
          ah[mt] = *(const half8*)(&sa[0][ky][px][8 * l4]);
          al[mt] = *(const half8*)(&sa[1][ky][px][8 * l4]);
        }
        half8 bh[2], bl[2];
        #pragma unroll
        for (int nt = 0; nt < 2; ++nt) {
          int oc = n0 + no + 16 * nt + l15;
          const _Float16* wp2 = wsp + ((long)(ky * 3 + kx) * COUT + oc) * CIN
                              + kc * 32 + 8 * l4;
          bh[nt] = *(const half8*)wp2;
          bl[nt] = *(const half8*)(wp2 + WPLANE);
        }
        #pragma unroll
        for (int mt = 0; mt < 2; ++mt) {
          #pragma unroll
          for (int nt = 0; nt < 2; ++nt) {
            acc[mt][nt] = __builtin_amdgcn_mfma_f32_16x16x32_f16(
                ah[mt], bh[nt], acc[mt][nt], 0, 0, 0);
            acc[mt][nt] = __builtin_amdgcn_mfma_f32_16x16x32_f16(
                al[mt], bh[nt], acc[mt][nt], 0, 0, 0);
            acc[mt][nt] = __builtin_amdgcn_mfma_f32_16x16x32_f16(
                ah[mt], bl[nt], acc[mt][nt], 0, 0, 0);
          }
        }
      }
    }
  }

  #pragma unroll
  for (int nt = 0; nt < 2; ++nt) {
    int oc = n0 + no + 16 * nt + l15;
    float bv = bias[oc];
    #pragma unroll
    for (int mt = 0; mt < 2; ++mt) {
      #pragma unroll
      for (int r = 0; r < 4; ++r) {
        float v = acc[mt][nt][r] + bv;
        v = v > 0.f ? v : 0.f;
        int m = mo + 16 * mt + l4 * 4 + r;
        if (LAST) {
          fout[(long)n * 131072 + (long)oc * (HOUT * WOUT)
               + (long)y * WOUT + (x0 + m)] = v;
        } else {
          _Float16 h, lo; splitf(v, h, lo);
          long addr = (long)n * SS_OUT
                    + ((long)(y + 1) * W2O + (x0 + m + 1)) * COUT + oc;
          aout[addr] = h;
          aout[PS_OUT + addr] = lo;
        }
      }
    }
  }
}

// ---------------------------------------------------------------------------
// MLP layer 1 (131072 -> 256), split-K with fp32 atomics. grid=(128,2).
// ---------------------------------------------------------------------------
__global__ __launch_bounds__(256) void mlp1_kernel(
    const float* __restrict__ feat, const float* __restrict__ kw1,
    const float* __restrict__ qw1, float* __restrict__ h1k,
    float* __restrict__ h1q)
{
  const int j = threadIdx.x;
  const int k0 = blockIdx.x * 1024;
  if (blockIdx.y == 0) {
    float acc[20];
    #pragma unroll
    for (int r = 0; r < 20; ++r) acc[r] = 0.f;
    for (int k = k0; k < k0 + 1024; ++k) {
      float wvv = kw1[(size_t)k * 256 + j];
      #pragma unroll
      for (int r = 0; r < 20; ++r)
        acc[r] += feat[(size_t)r * 131072 + k] * wvv;
    }
    #pragma unroll
    for (int r = 0; r < 20; ++r) atomicAdd(&h1k[r * 256 + j], acc[r]);
  } else {
    float acc[4];
    #pragma unroll
    for (int r = 0; r < 4; ++r) acc[r] = 0.f;
    for (int k = k0; k < k0 + 1024; ++k) {
      float wvv = qw1[(size_t)k * 256 + j];
      #pragma unroll
      for (int r = 0; r < 4; ++r)
        acc[r] += feat[(size_t)(r * 5) * 131072 + k] * wvv;
    }
    #pragma unroll
    for (int r = 0; r < 4; ++r) atomicAdd(&h1q[r * 256 + j], acc[r]);
  }
}

// ---------------------------------------------------------------------------
// MLP layers 2+3. grid = 24 blocks (20 key rows + 4 qry rows), 128 threads.
// ---------------------------------------------------------------------------
__global__ __launch_bounds__(128) void mlp2_kernel(
    const float* __restrict__ h1k, const float* __restrict__ h1q,
    const float* __restrict__ kb1, const float* __restrict__ kw2,
    const float* __restrict__ kb2, const float* __restrict__ kw3,
    const float* __restrict__ kb3,
    const float* __restrict__ qb1, const float* __restrict__ qw2,
    const float* __restrict__ qb2, const float* __restrict__ qw3,
    const float* __restrict__ qb3,
    float* __restrict__ keys, float* __restrict__ query)
{
  __shared__ float s1[256], s2[128];
  int r = blockIdx.x;
  bool isq = r >= 20;
  int row = isq ? (r - 20) : r;
  const float* h1 = (isq ? h1q : h1k) + row * 256;
  const float* b1 = isq ? qb1 : kb1;
  const float* W2 = isq ? qw2 : kw2;
  const float* b2v = isq ? qb2 : kb2;
  const float* W3 = isq ? qw3 : kw3;
  const float* b3 = isq ? qb3 : kb3;
  int N3 = isq ? 32 : 256;
  int t = threadIdx.x;
  for (int i = t; i < 256; i += 128) {
    float v = h1[i] + b1[i];
    s1[i] = v > 0.f ? v : 0.f;
  }
  __syncthreads();
  {
    float s = b2v[t];
    for (int k = 0; k < 256; ++k) s += s1[k] * W2[k * 128 + t];
    s2[t] = s > 0.f ? s : 0.f;
  }
  __syncthreads();
  for (int jj = t; jj < N3; jj += 128) {
    float s = b3[jj];
    for (int k = 0; k < 128; ++k) s += s2[k] * W3[k * N3 + jj];
    if (isq) query[row * 32 + jj] = s;
    else keys[row * 256 + jj] = s;
  }
}

// ---------------------------------------------------------------------------
// q = query@attn_w + b, scores, mask, sparsemax. 1 block.
// ---------------------------------------------------------------------------
__global__ __launch_bounds__(256) void scores_kernel(
    const float* __restrict__ keys, const float* __restrict__ query,
    const float* __restrict__ aw, const float* __restrict__ ab,
    const int* __restrict__ rec, float* __restrict__ attn)
{
  __shared__ float q[4][256];
  __shared__ float sc[20];
  int t = threadIdx.x;
  for (int u = t; u < 1024; u += 256) {
    int b = u >> 8, j = u & 255;
    float s = ab[j];
    for (int i = 0; i < 32; ++i) s += query[b * 32 + i] * aw[i * 256 + j];
    q[b][j] = s;
  }
  __syncthreads();
  if (t < 20) {
    int b = t / 5, l = t % 5;
    float s = 0.f;
    for (int j = 0; j < 256; ++j) s += keys[t * 256 + j] * q[b][j];
    sc[t] = (l < rec[b]) ? s : -1e9f;
  }
  __syncthreads();
  if (t < 4) {
    float z[5], zs[5];
    #pragma unroll
    for (int l = 0; l < 5; ++l) { z[l] = sc[t * 5 + l]; zs[l] = z[l]; }
    #pragma unroll
    for (int i = 0; i < 5; ++i)
      #pragma unroll
      for (int j2 = 0; j2 < 4; ++j2)
        if (zs[j2 + 1] > zs[j2]) { float tmp = zs[j2]; zs[j2] = zs[j2 + 1]; zs[j2 + 1] = tmp; }
    float css = 0.f, csel = 0.f; int ksel = 0;
    #pragma unroll
    for (int i = 0; i < 5; ++i) {
      css += zs[i];
      if (1.f + (float)(i + 1) * zs[i] > css) { ksel = i + 1; csel = css; }
    }
    float tau = (csel - 1.f) / (float)ksel;
    #pragma unroll
    for (int l = 0; l < 5; ++l) {
      float a = z[l] - tau;
      attn[t * 5 + l] = a > 0.f ? a : 0.f;
    }
  }
}

// ---------------------------------------------------------------------------
// Fusion: out[b,c,y,x] = sum_l attn[b,l] * bilinear(x[src(b,l)], c, y, x).
// Skips attn==0 maps. grid = (64 y, 4 c-chunks, 4 b), 256 thr = x.
// ---------------------------------------------------------------------------
__global__ __launch_bounds__(256) void fusion_kernel(
    const float* __restrict__ xin, const int* __restrict__ rec,
    const float* __restrict__ ptm, const float* __restrict__ attn,
    float* __restrict__ out)
{
  const int y = blockIdx.x;
  const int cc = blockIdx.y;
  const int b = blockIdx.z;
  const int x = threadIdx.x;
  int offs = 0;
  #pragma unroll
  for (int i = 0; i < 4; ++i) offs += (i < b) ? rec[i] : 0;
  int rb = rec[b];

  float av[5], a00[5], a01[5], a10[5], a11[5];
  int o00[5], o01[5], o10[5], o11[5];
  long sbase[5];
  #pragma unroll
  for (int l = 0; l < 5; ++l) {
    av[l] = attn[b * 5 + l];
    a00[l] = a01[l] = a10[l] = a11[l] = 0.f;
    o00[l] = o01[l] = o10[l] = o11[l] = 0;
    sbase[l] = 0;
    if (av[l] != 0.f && l < rb) {
      const float* M = ptm + ((size_t)b * 25 + l) * 6;
      float gx = (2.f * x + 1.f) / W_ - 1.f;
      float gy = (2.f * y + 1.f) / H_ - 1.f;
      float c0 = M[0] * gx + M[1] * gy + M[2];
      float c1 = M[3] * gx + M[4] * gy + M[5];
      float ix = ((c0 + 1.f) * W_ - 1.f) * 0.5f;
      float iy = ((c1 + 1.f) * H_ - 1.f) * 0.5f;
      float x0f = floorf(ix), y0f = floorf(iy);
      float wx = ix - x0f, wy = iy - y0f;
      bool vx0 = (x0f >= 0.f) && (x0f <= (float)(W_ - 1));
      bool vx1 = (x0f + 1.f >= 0.f) && (x0f + 1.f <= (float)(W_ - 1));
      bool vy0 = (y0f >= 0.f) && (y0f <= (float)(H_ - 1));
      bool vy1 = (y0f + 1.f >= 0.f) && (y0f + 1.f <= (float)(H_ - 1));
      int xi0 = min(max((int)x0f, 0), W_ - 1);
      int xi1 = min(max((int)x0f + 1, 0), W_ - 1);
      int yi0 = min(max((int)y0f, 0), H_ - 1);
      int yi1 = min(max((int)y0f + 1, 0), H_ - 1);
      a00[l] = (vx0 && vy0) ? (1.f - wy) * (1.f - wx) : 0.f;
      a01[l] = (vx1 && vy0) ? (1.f - wy) * wx : 0.f;
      a10[l] = (vx0 && vy1) ? wy * (1.f - wx) : 0.f;
      a11[l] = (vx1 && vy1) ? wy * wx : 0.f;
      o00[l] = yi0 * W_ + xi0; o01[l] = yi0 * W_ + xi1;
      o10[l] = yi1 * W_ + xi0; o11[l] = yi1 * W_ + xi1;
      sbase[l] = (long)(offs + l) * ((long)C_ * H_ * W_);
    }
  }
  for (int ci = 0; ci < 64; ++ci) {
    int c = cc * 64 + ci;
    float acc = 0.f;
    #pragma unroll
    for (int l = 0; l < 5; ++l) {
      if (av[l] != 0.f && l < rb) {
        const float* p = xin + sbase[l] + (long)c * (H_ * W_);
        acc += av[l] * (a00[l] * p[o00[l]] + a01[l] * p[o01[l]]
                      + a10[l] * p[o10[l]] + a11[l] * p[o11[l]]);
      }
    }
    out[((long)b * C_ + c) * (H_ * W_) + (long)y * W_ + x] = acc;
  }
}

// ---------------------------------------------------------------------------
extern "C" void kernel_launch(void* const* d_in, const int* in_sizes, int n_in,
                              void* d_out, int out_size, void* d_ws,
                              size_t ws_size, hipStream_t stream)
{
  const float* xin = (const float*)d_in[0];
  const int* rec = (const int*)d_in[1];
  const float* ptm = (const float*)d_in[2];
  const float* c1w = (const float*)d_in[3];
  const float* s1 = (const float*)d_in[4];
  const float* b1 = (const float*)d_in[5];
  const float* c2w = (const float*)d_in[6];
  const float* s2 = (const float*)d_in[7];
  const float* b2 = (const float*)d_in[8];
  const float* c3w = (const float*)d_in[9];
  const float* s3 = (const float*)d_in[10];
  const float* b3 = (const float*)d_in[11];
  const float* c4w = (const float*)d_in[12];
  const float* s4 = (const float*)d_in[13];
  const float* b4 = (const float*)d_in[14];
  const float* c5w = (const float*)d_in[15];
  const float* s5 = (const float*)d_in[16];
  const float* b5 = (const float*)d_in[17];
  const float* kw1 = (const float*)d_in[18];
  const float* kb1 = (const float*)d_in[19];
  const float* kw2 = (const float*)d_in[20];
  const float* kb2 = (const float*)d_in[21];
  const float* kw3 = (const float*)d_in[22];
  const float* kb3 = (const float*)d_in[23];
  const float* qw1 = (const float*)d_in[24];
  const float* qb1 = (const float*)d_in[25];
  const float* qw2 = (const float*)d_in[26];
  const float* qb2 = (const float*)d_in[27];
  const float* qw3 = (const float*)d_in[28];
  const float* qb3 = (const float*)d_in[29];
  const float* aw = (const float*)d_in[30];
  const float* ab = (const float*)d_in[31];
  float* out = (float*)d_out;
  char* ws = (char*)d_ws;

  // workspace layout (bytes); all offsets 256-aligned
  constexpr size_t SZ_ACT0 = (size_t)66 * 258 * 256 * NS * 2 * 2; // 348,733,440
  constexpr size_t SZ_ACT1 = (size_t)66 * 258 * 32 * NS * 2 * 2;  // 43,591,680
  constexpr size_t SZ_ACT3 = (size_t)34 * 130 * 64 * NS * 2 * 2;  // 22,630,400
  constexpr size_t SZ_FEAT = (size_t)NS * 131072 * 4;             // 10,485,760
  constexpr size_t o_act0 = 0;
  constexpr size_t o_act1 = o_act0 + SZ_ACT0;
  constexpr size_t o_act2 = o_act1 + SZ_ACT1;
  constexpr size_t o_act3 = o_act2 + SZ_ACT1;
  constexpr size_t o_act4 = o_act3 + SZ_ACT3;
  constexpr size_t o_feat = o_act4 + SZ_ACT3;
  constexpr size_t o_w1 = o_feat + SZ_FEAT;
  constexpr size_t o_w2 = o_w1 + (size_t)73728 * 4;
  constexpr size_t o_w3 = o_w2 + (size_t)9216 * 4;
  constexpr size_t o_w4 = o_w3 + (size_t)18432 * 4;
  constexpr size_t o_w5 = o_w4 + (size_t)36864 * 4;
  constexpr size_t o_h1k = o_w5 + (size_t)73728 * 4;
  constexpr size_t o_h1q = o_h1k + 20480;
  constexpr size_t o_keys = o_h1q + 4096;
  constexpr size_t o_query = o_keys + 20480;
  constexpr size_t o_attn = o_query + 512;

  _Float16* act0 = (_Float16*)(ws + o_act0);
  _Float16* act1 = (_Float16*)(ws + o_act1);
  _Float16* act2 = (_Float16*)(ws + o_act2);
  _Float16* act3 = (_Float16*)(ws + o_act3);
  _Float16* act4 = (_Float16*)(ws + o_act4);
  float* feat = (float*)(ws + o_feat);
  _Float16* w1s = (_Float16*)(ws + o_w1);
  _Float16* w2s = (_Float16*)(ws + o_w2);
  _Float16* w3s = (_Float16*)(ws + o_w3);
  _Float16* w4s = (_Float16*)(ws + o_w4);
  _Float16* w5s = (_Float16*)(ws + o_w5);
  float* h1k = (float*)(ws + o_h1k);
  float* h1q = (float*)(ws + o_h1q);
  float* keys = (float*)(ws + o_keys);
  float* query = (float*)(ws + o_query);
  float* attnb = (float*)(ws + o_attn);

  hipMemsetAsync(ws + o_h1k, 0, 24576, stream);

  prep_w_kernel<<<dim3(829), 256, 0, stream>>>(
      c1w, s1, c2w, s2, c3w, s3, c4w, s4, c5w, s5, w1s, w2s, w3s, w4s, w5s);

  zero_border_kernel<<<dim3(3220), 256, 0, stream>>>(
      act0, 66, 258, 256, (size_t)66 * 258 * 256 * NS);
  zero_border_kernel<<<dim3(403), 256, 0, stream>>>(
      act1, 66, 258, 32, (size_t)66 * 258 * 32 * NS);
  zero_border_kernel<<<dim3(403), 256, 0, stream>>>(
      act2, 66, 258, 32, (size_t)66 * 258 * 32 * NS);
  zero_border_kernel<<<dim3(405), 256, 0, stream>>>(
      act3, 34, 130, 64, (size_t)34 * 130 * 64 * NS);
  zero_border_kernel<<<dim3(405), 256, 0, stream>>>(
      act4, 34, 130, 64, (size_t)34 * 130 * 64 * NS);

  warp_split_kernel<<<dim3(64, 20), 256, 0, stream>>>(xin, rec, ptm, act0);

  conv_kernel<256, 32, 64, 256, 1, 128, 32, 1, 0>
      <<<dim3(128, 1, 20), 256, 0, stream>>>(act0, w1s, b1, act1, (float*)nullptr);
  conv_kernel<32, 32, 64, 256, 1, 128, 32, 1, 0>
      <<<dim3(128, 1, 20), 256, 0, stream>>>(act1, w2s, b2, act2, (float*)nullptr);
  conv_kernel<32, 64, 64, 256, 2, 64, 64, 2, 0>
      <<<dim3(64, 1, 20), 256, 0, stream>>>(act2, w3s, b3, act3, (float*)nullptr);
  conv_kernel<64, 64, 32, 128, 1, 64, 64, 2, 0>
      <<<dim3(64, 1, 20), 256, 0, stream>>>(act3, w4s, b4, act4, (float*)nullptr);
  conv_kernel<64, 128, 32, 128, 2, 64, 64, 2, 1>
      <<<dim3(16, 2, 20), 256, 0, stream>>>(act4, w5s, b5, (_Float16*)nullptr, feat);

  mlp1_kernel<<<dim3(128, 2), 256, 0, stream>>>(feat, kw1, qw1, h1k, h1q);
  mlp2_kernel<<<dim3(24), 128, 0, stream>>>(
      h1k, h1q, kb1, kw2, kb2, kw3, kb3, qb1, qw2, qb2, qw3, qb3, keys, query);
  scores_kernel<<<dim3(1), 256, 0, stream>>>(keys, query, aw, ab, rec, attnb);
  fusion_kernel<<<dim3(64, 4, 4), 256, 0, stream>>>(xin, rec, ptm, attnb, out);
}

// Round 2
// 1876.741 us; speedup vs baseline: 1.4829x; 1.4829x over previous
//
#include <hip/hip_runtime.h>
#include <hip/hip_bf16.h>
#include <cstdint>
#include <cstddef>

// ---------------------------------------------------------------------------
// When2commFusion on MI355X.
// Pipeline: scatter+affine-warp -> 5x conv3x3/BN/ReLU (fp16 hi/lo split MFMA,
// fp32 accum) -> key/query MLPs (fp32) -> sparsemax -> weighted re-warp fusion.
// R1: mlp1 rebuilt as two-stage split-K (was 990us latency-bound @1.9% HBM).
// ---------------------------------------------------------------------------

typedef _Float16 half8 __attribute__((ext_vector_type(8)));
typedef float f32x4 __attribute__((ext_vector_type(4)));

#define B_ 4
#define L_ 5
#define C_ 256
#define H_ 64
#define W_ 256
#define NS 20

__device__ __forceinline__ void splitf(float v, _Float16& h, _Float16& l) {
  _Float16 hh = (_Float16)v;
  h = hh;
  l = (_Float16)(v - (float)hh);
}

// ---------------------------------------------------------------------------
// Weight prep: fold BN scale, transpose to [tap][oc][ic], split fp16 hi/lo.
// ---------------------------------------------------------------------------
__global__ __launch_bounds__(256) void prep_w_kernel(
    const float* __restrict__ w1, const float* __restrict__ s1,
    const float* __restrict__ w2, const float* __restrict__ s2,
    const float* __restrict__ w3, const float* __restrict__ s3,
    const float* __restrict__ w4, const float* __restrict__ s4,
    const float* __restrict__ w5, const float* __restrict__ s5,
    _Float16* __restrict__ o1, _Float16* __restrict__ o2,
    _Float16* __restrict__ o3, _Float16* __restrict__ o4,
    _Float16* __restrict__ o5)
{
  const int sz[5]   = {73728, 9216, 18432, 36864, 73728};
  const int cin[5]  = {256, 32, 32, 64, 64};
  const int cout[5] = {32, 32, 64, 64, 128};
  const float* wp[5] = {w1, w2, w3, w4, w5};
  const float* sp[5] = {s1, s2, s3, s4, s5};
  _Float16* op[5] = {o1, o2, o3, o4, o5};

  int e = blockIdx.x * 256 + threadIdx.x;
  if (e >= 211968) return;
  int lay = 0, base = 0;
  while (lay < 4 && e >= base + sz[lay]) { base += sz[lay]; ++lay; }
  int local = e - base;
  int CIN = cin[lay], COUT = cout[lay];
  int oc = local / (CIN * 9);
  int ic = (local / 9) % CIN;
  int t  = local % 9;
  float v = wp[lay][local] * sp[lay][oc];
  _Float16 h, lo; splitf(v, h, lo);
  int planeS = 9 * COUT * CIN;
  int dst = (t * COUT + oc) * CIN + ic;
  op[lay][dst] = h;
  op[lay][planeS + dst] = lo;
}

// ---------------------------------------------------------------------------
// Zero the 1-px padding border of a padded-NHWC activation buffer (2 planes).
// ---------------------------------------------------------------------------
__global__ __launch_bounds__(256) void zero_border_kernel(
    _Float16* __restrict__ act, int H2, int W2, int C, size_t planeStride)
{
  long u = (long)blockIdx.x * 256 + threadIdx.x;
  int borderPx = 2 * W2 + 2 * (H2 - 2);
  int c8n = C >> 3;
  long total = (long)borderPx * c8n * NS * 2;
  if (u >= total) return;
  int c8 = (int)(u % c8n); long t = u / c8n;
  int bp = (int)(t % borderPx); t /= borderPx;
  int n = (int)(t % NS); int pl = (int)(t / NS);
  int yy, xx;
  if (bp < 2 * W2) { yy = (bp < W2) ? 0 : (H2 - 1); xx = bp % W2; }
  else { int j = bp - 2 * W2; xx = (j & 1) ? (W2 - 1) : 0; yy = 1 + (j >> 1); }
  size_t addr = (size_t)pl * planeStride + (size_t)n * ((size_t)H2 * W2 * C)
              + ((size_t)yy * W2 + xx) * C + (size_t)c8 * 8;
  half8 z = {};
  *(half8*)(act + addr) = z;
}

// ---------------------------------------------------------------------------
// Scatter + affine warp + fp16 split, writing conv1 input (padded NHWC hi/lo).
// ---------------------------------------------------------------------------
__global__ __launch_bounds__(256) void warp_split_kernel(
    const float* __restrict__ xin, const int* __restrict__ rec,
    const float* __restrict__ ptm, _Float16* __restrict__ act0)
{
  const int y = blockIdx.x;
  const int n = blockIdx.y;
  const int x = threadIdx.x;
  const int b = n / L_, l = n % L_;
  int offs = 0;
  #pragma unroll
  for (int i = 0; i < 4; ++i) offs += (i < b) ? rec[i] : 0;
  const bool valid = l < rec[b];
  const int src = offs + l;

  __shared__ float tile[256][33];

  const float* M = ptm + ((size_t)b * 25 + l) * 6;
  float gx = (2.f * x + 1.f) / W_ - 1.f;
  float gy = (2.f * y + 1.f) / H_ - 1.f;
  float c0 = M[0] * gx + M[1] * gy + M[2];
  float c1 = M[3] * gx + M[4] * gy + M[5];
  float ix = ((c0 + 1.f) * W_ - 1.f) * 0.5f;
  float iy = ((c1 + 1.f) * H_ - 1.f) * 0.5f;
  float x0f = floorf(ix), y0f = floorf(iy);
  float wx = ix - x0f, wy = iy - y0f;
  bool vx0 = (x0f >= 0.f) && (x0f <= (float)(W_ - 1));
  bool vx1 = (x0f + 1.f >= 0.f) && (x0f + 1.f <= (float)(W_ - 1));
  bool vy0 = (y0f >= 0.f) && (y0f <= (float)(H_ - 1));
  bool vy1 = (y0f + 1.f >= 0.f) && (y0f + 1.f <= (float)(H_ - 1));
  int xi0 = min(max((int)x0f, 0), W_ - 1);
  int xi1 = min(max((int)x0f + 1, 0), W_ - 1);
  int yi0 = min(max((int)y0f, 0), H_ - 1);
  int yi1 = min(max((int)y0f + 1, 0), H_ - 1);
  float a00 = (vx0 && vy0) ? (1.f - wy) * (1.f - wx) : 0.f;
  float a01 = (vx1 && vy0) ? (1.f - wy) * wx : 0.f;
  float a10 = (vx0 && vy1) ? wy * (1.f - wx) : 0.f;
  float a11 = (vx1 && vy1) ? wy * wx : 0.f;
  int o00 = yi0 * W_ + xi0, o01 = yi0 * W_ + xi1;
  int o10 = yi1 * W_ + xi0, o11 = yi1 * W_ + xi1;
  const float* sb = xin + (size_t)src * (C_ * H_ * W_);

  const size_t SS0 = (size_t)66 * 258 * 256;
  const size_t PS0 = SS0 * NS;

  for (int cc = 0; cc < 8; ++cc) {
    __syncthreads();
    #pragma unroll 4
    for (int ci = 0; ci < 32; ++ci) {
      int c = cc * 32 + ci;
      float v = 0.f;
      if (valid) {
        const float* p = sb + (size_t)c * (H_ * W_);
        v = a00 * p[o00] + a01 * p[o01] + a10 * p[o10] + a11 * p[o11];
      }
      tile[x][ci] = v;
    }
    __syncthreads();
    for (int u = threadIdx.x; u < 8192; u += 256) {
      int px = u >> 5, ci = u & 31;
      float v = tile[px][ci];
      _Float16 h, lo; splitf(v, h, lo);
      size_t addr = (size_t)n * SS0 + ((size_t)(y + 1) * 258 + (px + 1)) * 256
                  + cc * 32 + ci;
      act0[addr] = h;
      act0[PS0 + addr] = lo;
    }
  }
}

// ---------------------------------------------------------------------------
// Implicit-GEMM conv3x3 + BN bias + ReLU, fp16 hi/lo split, 16x16x32 MFMA.
// ---------------------------------------------------------------------------
template<int CIN, int COUT, int HIN, int WIN, int STRIDE, int BM, int BN,
         int WC, int LAST>
__global__ __launch_bounds__(256, 2) void conv_kernel(
    const _Float16* __restrict__ ain, const _Float16* __restrict__ wsp,
    const float* __restrict__ bias, _Float16* __restrict__ aout,
    float* __restrict__ fout)
{
  constexpr int H2 = HIN + 2, W2 = WIN + 2;
  constexpr int HOUT = HIN / STRIDE, WOUT = WIN / STRIDE;
  constexpr int XT = WOUT / BM;
  constexpr int WS = (STRIDE == 1) ? (BM + 2) : (2 * BM + 2);
  constexpr int KC = CIN / 32;
  constexpr long SS_IN = (long)H2 * W2 * CIN;
  constexpr long PS_IN = (long)NS * SS_IN;
  constexpr int H2O = HOUT + 2, W2O = WOUT + 2;
  constexpr long SS_OUT = (long)H2O * W2O * COUT;
  constexpr long PS_OUT = (long)NS * SS_OUT;
  constexpr int WPLANE = 9 * COUT * CIN;

  __shared__ _Float16 sa[2][3][WS][40];

  const int mb = blockIdx.x;
  const int y = mb / XT;
  const int x0 = (mb % XT) * BM;
  const int n0 = blockIdx.y * BN;
  const int n = blockIdx.z;
  const int tid = threadIdx.x;
  const int lane = tid & 63;
  const int wv = tid >> 6;
  const int mo = 32 * (wv / WC);
  const int no = 32 * (wv % WC);
  const int l15 = lane & 15, l4 = lane >> 4;

  f32x4 acc[2][2] = {};
  const _Float16* inb = ain + (long)n * SS_IN;

  for (int kc = 0; kc < KC; ++kc) {
    __syncthreads();
    {
      const int units = 3 * WS * 4;
      #pragma unroll
      for (int pl = 0; pl < 2; ++pl) {
        const _Float16* src_base = inb + (long)pl * PS_IN + kc * 32;
        for (int u = tid; u < units; u += 256) {
          int ky = u / (WS * 4);
          int r = u - ky * (WS * 4);
          int px = r >> 2, c8 = r & 3;
          int gy = y * STRIDE + ky;
          int gx = x0 * STRIDE + px;
          const _Float16* spp = src_base + ((long)gy * W2 + gx) * CIN + c8 * 8;
          *(half8*)(&sa[pl][ky][px][c8 * 8]) = *(const half8*)spp;
        }
      }
    }
    __syncthreads();
    #pragma unroll
    for (int ky = 0; ky < 3; ++ky) {
      #pragma unroll
      for (int kx = 0; kx < 3; ++kx) {
        half8 ah[2], al[2];
        #pragma unroll
        for (int mt = 0; mt < 2; ++mt) {
          int px = (mo + 16 * mt + l15) * STRIDE + kx;
          ah[mt] = *(const half8*)(&sa[0][ky][px][8 * l4]);
          al[mt] = *(const half8*)(&sa[1][ky][px][8 * l4]);
        }
        half8 bh[2], bl[2];
        #pragma unroll
        for (int nt = 0; nt < 2; ++nt) {
          int oc = n0 + no + 16 * nt + l15;
          const _Float16* wp2 = wsp + ((long)(ky * 3 + kx) * COUT + oc) * CIN
                              + kc * 32 + 8 * l4;
          bh[nt] = *(const half8*)wp2;
          bl[nt] = *(const half8*)(wp2 + WPLANE);
        }
        #pragma unroll
        for (int mt = 0; mt < 2; ++mt) {
          #pragma unroll
          for (int nt = 0; nt < 2; ++nt) {
            acc[mt][nt] = __builtin_amdgcn_mfma_f32_16x16x32_f16(
                ah[mt], bh[nt], acc[mt][nt], 0, 0, 0);
            acc[mt][nt] = __builtin_amdgcn_mfma_f32_16x16x32_f16(
                al[mt], bh[nt], acc[mt][nt], 0, 0, 0);
            acc[mt][nt] = __builtin_amdgcn_mfma_f32_16x16x32_f16(
                ah[mt], bl[nt], acc[mt][nt], 0, 0, 0);
          }
        }
      }
    }
  }

  #pragma unroll
  for (int nt = 0; nt < 2; ++nt) {
    int oc = n0 + no + 16 * nt + l15;
    float bv = bias[oc];
    #pragma unroll
    for (int mt = 0; mt < 2; ++mt) {
      #pragma unroll
      for (int r = 0; r < 4; ++r) {
        float v = acc[mt][nt][r] + bv;
        v = v > 0.f ? v : 0.f;
        int m = mo + 16 * mt + l4 * 4 + r;
        if (LAST) {
          fout[(long)n * 131072 + (long)oc * (HOUT * WOUT)
               + (long)y * WOUT + (x0 + m)] = v;
        } else {
          _Float16 h, lo; splitf(v, h, lo);
          long addr = (long)n * SS_OUT
                    + ((long)(y + 1) * W2O + (x0 + m + 1)) * COUT + oc;
          aout[addr] = h;
          aout[PS_OUT + addr] = lo;
        }
      }
    }
  }
}

// ---------------------------------------------------------------------------
// MLP layer 1 stage A: split-K partials. grid.x = 512 k-slabs (256 k each).
// Each wave handles k = slab + wv (mod 4), streaming W rows as float4
// (64 lanes x 16B = 1KB coalesced). feat slab staged in LDS (broadcast reads).
// R accumulator chains/lane give ILP; partial chunk p = blockIdx.x*4 + wave.
// rstride: feat row for r is r*rstride (key: 1, qry: 5 -> rows 0,5,10,15).
// ---------------------------------------------------------------------------
template<int R>
__global__ __launch_bounds__(256) void mlp1a_kernel(
    const float* __restrict__ feat, const float* __restrict__ Wm,
    float* __restrict__ part, int rstride)
{
  const int slab = blockIdx.x * 256;
  const int tid = threadIdx.x;
  const int wv = tid >> 6, lane = tid & 63;
  __shared__ float sf[R][256];
  for (int u = tid; u < R * 256; u += 256) {
    int r = u >> 8, kk = u & 255;
    sf[r][kk] = feat[(size_t)(r * rstride) * 131072 + slab + kk];
  }
  __syncthreads();

  f32x4 acc[R];
  #pragma unroll
  for (int r = 0; r < R; ++r) acc[r] = f32x4{0.f, 0.f, 0.f, 0.f};

  const f32x4* Wv = (const f32x4*)Wm;
  #pragma unroll 2
  for (int kk = wv; kk < 256; kk += 4) {
    f32x4 w4 = Wv[(size_t)(slab + kk) * 64 + lane];
    #pragma unroll
    for (int r = 0; r < R; ++r) {
      float s = sf[r][kk];
      acc[r] += w4 * s;
    }
  }

  const int p = blockIdx.x * 4 + wv;  // 2048 partial chunks
  f32x4* outp = (f32x4*)part;
  #pragma unroll
  for (int r = 0; r < R; ++r)
    outp[((size_t)p * R + r) * 64 + lane] = acc[r];
}

// ---------------------------------------------------------------------------
// MLP layer 1 stage B: reduce 2048 partial chunks. grid=(24 rows, 16 groups).
// ---------------------------------------------------------------------------
__global__ __launch_bounds__(256) void mlp1b_kernel(
    const float* __restrict__ pk, const float* __restrict__ pq,
    float* __restrict__ h1k, float* __restrict__ h1q)
{
  int rr = blockIdx.x;       // 0..19 key, 20..23 qry
  int g = blockIdx.y;        // 0..15
  int j = threadIdx.x;
  bool isq = rr >= 20;
  int r = isq ? rr - 20 : rr;
  int R = isq ? 4 : 20;
  const float* P = isq ? pq : pk;
  float s = 0.f;
  #pragma unroll 8
  for (int p = g * 128; p < (g + 1) * 128; ++p)
    s += P[((size_t)p * R + r) * 256 + j];
  atomicAdd((isq ? h1q : h1k) + r * 256 + j, s);
}

// ---------------------------------------------------------------------------
// MLP layers 2+3. grid = 24 blocks (20 key rows + 4 qry rows), 128 threads.
// ---------------------------------------------------------------------------
__global__ __launch_bounds__(128) void mlp2_kernel(
    const float* __restrict__ h1k, const float* __restrict__ h1q,
    const float* __restrict__ kb1, const float* __restrict__ kw2,
    const float* __restrict__ kb2, const float* __restrict__ kw3,
    const float* __restrict__ kb3,
    const float* __restrict__ qb1, const float* __restrict__ qw2,
    const float* __restrict__ qb2, const float* __restrict__ qw3,
    const float* __restrict__ qb3,
    float* __restrict__ keys, float* __restrict__ query)
{
  __shared__ float s1[256], s2[128];
  int r = blockIdx.x;
  bool isq = r >= 20;
  int row = isq ? (r - 20) : r;
  const float* h1 = (isq ? h1q : h1k) + row * 256;
  const float* b1 = isq ? qb1 : kb1;
  const float* W2 = isq ? qw2 : kw2;
  const float* b2v = isq ? qb2 : kb2;
  const float* W3 = isq ? qw3 : kw3;
  const float* b3 = isq ? qb3 : kb3;
  int N3 = isq ? 32 : 256;
  int t = threadIdx.x;
  for (int i = t; i < 256; i += 128) {
    float v = h1[i] + b1[i];
    s1[i] = v > 0.f ? v : 0.f;
  }
  __syncthreads();
  {
    float s = b2v[t];
    for (int k = 0; k < 256; ++k) s += s1[k] * W2[k * 128 + t];
    s2[t] = s > 0.f ? s : 0.f;
  }
  __syncthreads();
  for (int jj = t; jj < N3; jj += 128) {
    float s = b3[jj];
    for (int k = 0; k < 128; ++k) s += s2[k] * W3[k * N3 + jj];
    if (isq) query[row * 32 + jj] = s;
    else keys[row * 256 + jj] = s;
  }
}

// ---------------------------------------------------------------------------
// q = query@attn_w + b, scores, mask, sparsemax. 1 block.
// ---------------------------------------------------------------------------
__global__ __launch_bounds__(256) void scores_kernel(
    const float* __restrict__ keys, const float* __restrict__ query,
    const float* __restrict__ aw, const float* __restrict__ ab,
    const int* __restrict__ rec, float* __restrict__ attn)
{
  __shared__ float q[4][256];
  __shared__ float sc[20];
  int t = threadIdx.x;
  for (int u = t; u < 1024; u += 256) {
    int b = u >> 8, j = u & 255;
    float s = ab[j];
    for (int i = 0; i < 32; ++i) s += query[b * 32 + i] * aw[i * 256 + j];
    q[b][j] = s;
  }
  __syncthreads();
  if (t < 20) {
    int b = t / 5, l = t % 5;
    float s = 0.f;
    for (int j = 0; j < 256; ++j) s += keys[t * 256 + j] * q[b][j];
    sc[t] = (l < rec[b]) ? s : -1e9f;
  }
  __syncthreads();
  if (t < 4) {
    float z[5], zs[5];
    #pragma unroll
    for (int l = 0; l < 5; ++l) { z[l] = sc[t * 5 + l]; zs[l] = z[l]; }
    #pragma unroll
    for (int i = 0; i < 5; ++i)
      #pragma unroll
      for (int j2 = 0; j2 < 4; ++j2)
        if (zs[j2 + 1] > zs[j2]) { float tmp = zs[j2]; zs[j2] = zs[j2 + 1]; zs[j2 + 1] = tmp; }
    float css = 0.f, csel = 0.f; int ksel = 0;
    #pragma unroll
    for (int i = 0; i < 5; ++i) {
      css += zs[i];
      if (1.f + (float)(i + 1) * zs[i] > css) { ksel = i + 1; csel = css; }
    }
    float tau = (csel - 1.f) / (float)ksel;
    #pragma unroll
    for (int l = 0; l < 5; ++l) {
      float a = z[l] - tau;
      attn[t * 5 + l] = a > 0.f ? a : 0.f;
    }
  }
}

// ---------------------------------------------------------------------------
// Fusion: out[b,c,y,x] = sum_l attn[b,l] * bilinear(x[src(b,l)], c, y, x).
// ---------------------------------------------------------------------------
__global__ __launch_bounds__(256) void fusion_kernel(
    const float* __restrict__ xin, const int* __restrict__ rec,
    const float* __restrict__ ptm, const float* __restrict__ attn,
    float* __restrict__ out)
{
  const int y = blockIdx.x;
  const int cc = blockIdx.y;
  const int b = blockIdx.z;
  const int x = threadIdx.x;
  int offs = 0;
  #pragma unroll
  for (int i = 0; i < 4; ++i) offs += (i < b) ? rec[i] : 0;
  int rb = rec[b];

  float av[5], a00[5], a01[5], a10[5], a11[5];
  int o00[5], o01[5], o10[5], o11[5];
  long sbase[5];
  #pragma unroll
  for (int l = 0; l < 5; ++l) {
    av[l] = attn[b * 5 + l];
    a00[l] = a01[l] = a10[l] = a11[l] = 0.f;
    o00[l] = o01[l] = o10[l] = o11[l] = 0;
    sbase[l] = 0;
    if (av[l] != 0.f && l < rb) {
      const float* M = ptm + ((size_t)b * 25 + l) * 6;
      float gx = (2.f * x + 1.f) / W_ - 1.f;
      float gy = (2.f * y + 1.f) / H_ - 1.f;
      float c0 = M[0] * gx + M[1] * gy + M[2];
      float c1 = M[3] * gx + M[4] * gy + M[5];
      float ix = ((c0 + 1.f) * W_ - 1.f) * 0.5f;
      float iy = ((c1 + 1.f) * H_ - 1.f) * 0.5f;
      float x0f = floorf(ix), y0f = floorf(iy);
      float wx = ix - x0f, wy = iy - y0f;
      bool vx0 = (x0f >= 0.f) && (x0f <= (float)(W_ - 1));
      bool vx1 = (x0f + 1.f >= 0.f) && (x0f + 1.f <= (float)(W_ - 1));
      bool vy0 = (y0f >= 0.f) && (y0f <= (float)(H_ - 1));
      bool vy1 = (y0f + 1.f >= 0.f) && (y0f + 1.f <= (float)(H_ - 1));
      int xi0 = min(max((int)x0f, 0), W_ - 1);
      int xi1 = min(max((int)x0f + 1, 0), W_ - 1);
      int yi0 = min(max((int)y0f, 0), H_ - 1);
      int yi1 = min(max((int)y0f + 1, 0), H_ - 1);
      a00[l] = (vx0 && vy0) ? (1.f - wy) * (1.f - wx) : 0.f;
      a01[l] = (vx1 && vy0) ? (1.f - wy) * wx : 0.f;
      a10[l] = (vx0 && vy1) ? wy * (1.f - wx) : 0.f;
      a11[l] = (vx1 && vy1) ? wy * wx : 0.f;
      o00[l] = yi0 * W_ + xi0; o01[l] = yi0 * W_ + xi1;
      o10[l] = yi1 * W_ + xi0; o11[l] = yi1 * W_ + xi1;
      sbase[l] = (long)(offs + l) * ((long)C_ * H_ * W_);
    }
  }
  for (int ci = 0; ci < 64; ++ci) {
    int c = cc * 64 + ci;
    float acc = 0.f;
    #pragma unroll
    for (int l = 0; l < 5; ++l) {
      if (av[l] != 0.f && l < rb) {
        const float* p = xin + sbase[l] + (long)c * (H_ * W_);
        acc += av[l] * (a00[l] * p[o00[l]] + a01[l] * p[o01[l]]
                      + a10[l] * p[o10[l]] + a11[l] * p[o11[l]]);
      }
    }
    out[((long)b * C_ + c) * (H_ * W_) + (long)y * W_ + x] = acc;
  }
}

// ---------------------------------------------------------------------------
extern "C" void kernel_launch(void* const* d_in, const int* in_sizes, int n_in,
                              void* d_out, int out_size, void* d_ws,
                              size_t ws_size, hipStream_t stream)
{
  const float* xin = (const float*)d_in[0];
  const int* rec = (const int*)d_in[1];
  const float* ptm = (const float*)d_in[2];
  const float* c1w = (const float*)d_in[3];
  const float* s1 = (const float*)d_in[4];
  const float* b1 = (const float*)d_in[5];
  const float* c2w = (const float*)d_in[6];
  const float* s2 = (const float*)d_in[7];
  const float* b2 = (const float*)d_in[8];
  const float* c3w = (const float*)d_in[9];
  const float* s3 = (const float*)d_in[10];
  const float* b3 = (const float*)d_in[11];
  const float* c4w = (const float*)d_in[12];
  const float* s4 = (const float*)d_in[13];
  const float* b4 = (const float*)d_in[14];
  const float* c5w = (const float*)d_in[15];
  const float* s5 = (const float*)d_in[16];
  const float* b5 = (const float*)d_in[17];
  const float* kw1 = (const float*)d_in[18];
  const float* kb1 = (const float*)d_in[19];
  const float* kw2 = (const float*)d_in[20];
  const float* kb2 = (const float*)d_in[21];
  const float* kw3 = (const float*)d_in[22];
  const float* kb3 = (const float*)d_in[23];
  const float* qw1 = (const float*)d_in[24];
  const float* qb1 = (const float*)d_in[25];
  const float* qw2 = (const float*)d_in[26];
  const float* qb2 = (const float*)d_in[27];
  const float* qw3 = (const float*)d_in[28];
  const float* qb3 = (const float*)d_in[29];
  const float* aw = (const float*)d_in[30];
  const float* ab = (const float*)d_in[31];
  float* out = (float*)d_out;
  char* ws = (char*)d_ws;

  // workspace layout (bytes); all offsets 256-aligned
  constexpr size_t SZ_ACT0 = (size_t)66 * 258 * 256 * NS * 2 * 2; // 348,733,440
  constexpr size_t SZ_ACT1 = (size_t)66 * 258 * 32 * NS * 2 * 2;  // 43,591,680
  constexpr size_t SZ_ACT3 = (size_t)34 * 130 * 64 * NS * 2 * 2;  // 22,630,400
  constexpr size_t SZ_FEAT = (size_t)NS * 131072 * 4;             // 10,485,760
  constexpr size_t o_act0 = 0;
  constexpr size_t o_act1 = o_act0 + SZ_ACT0;
  constexpr size_t o_act2 = o_act1 + SZ_ACT1;
  constexpr size_t o_act3 = o_act2 + SZ_ACT1;
  constexpr size_t o_act4 = o_act3 + SZ_ACT3;
  constexpr size_t o_feat = o_act4 + SZ_ACT3;
  constexpr size_t o_w1 = o_feat + SZ_FEAT;
  constexpr size_t o_w2 = o_w1 + (size_t)73728 * 4;
  constexpr size_t o_w3 = o_w2 + (size_t)9216 * 4;
  constexpr size_t o_w4 = o_w3 + (size_t)18432 * 4;
  constexpr size_t o_w5 = o_w4 + (size_t)36864 * 4;
  constexpr size_t o_h1k = o_w5 + (size_t)73728 * 4;
  constexpr size_t o_h1q = o_h1k + 20480;
  constexpr size_t o_keys = o_h1q + 4096;
  constexpr size_t o_query = o_keys + 20480;
  constexpr size_t o_attn = o_query + 512;
  // mlp1 partials alias the act0 region (act0 is dead after conv1):
  constexpr size_t o_pk = 0;                        // 2048*20*256*4 = 41.9 MB
  constexpr size_t o_pq = (size_t)2048 * 20 * 256 * 4;  // 2048*4*256*4 = 8.4 MB

  _Float16* act0 = (_Float16*)(ws + o_act0);
  _Float16* act1 = (_Float16*)(ws + o_act1);
  _Float16* act2 = (_Float16*)(ws + o_act2);
  _Float16* act3 = (_Float16*)(ws + o_act3);
  _Float16* act4 = (_Float16*)(ws + o_act4);
  float* feat = (float*)(ws + o_feat);
  _Float16* w1s = (_Float16*)(ws + o_w1);
  _Float16* w2s = (_Float16*)(ws + o_w2);
  _Float16* w3s = (_Float16*)(ws + o_w3);
  _Float16* w4s = (_Float16*)(ws + o_w4);
  _Float16* w5s = (_Float16*)(ws + o_w5);
  float* h1k = (float*)(ws + o_h1k);
  float* h1q = (float*)(ws + o_h1q);
  float* keys = (float*)(ws + o_keys);
  float* query = (float*)(ws + o_query);
  float* attnb = (float*)(ws + o_attn);
  float* pk = (float*)(ws + o_pk);
  float* pq = (float*)(ws + o_pq);

  hipMemsetAsync(ws + o_h1k, 0, 24576, stream);

  prep_w_kernel<<<dim3(829), 256, 0, stream>>>(
      c1w, s1, c2w, s2, c3w, s3, c4w, s4, c5w, s5, w1s, w2s, w3s, w4s, w5s);

  zero_border_kernel<<<dim3(3220), 256, 0, stream>>>(
      act0, 66, 258, 256, (size_t)66 * 258 * 256 * NS);
  zero_border_kernel<<<dim3(403), 256, 0, stream>>>(
      act1, 66, 258, 32, (size_t)66 * 258 * 32 * NS);
  zero_border_kernel<<<dim3(403), 256, 0, stream>>>(
      act2, 66, 258, 32, (size_t)66 * 258 * 32 * NS);
  zero_border_kernel<<<dim3(405), 256, 0, stream>>>(
      act3, 34, 130, 64, (size_t)34 * 130 * 64 * NS);
  zero_border_kernel<<<dim3(405), 256, 0, stream>>>(
      act4, 34, 130, 64, (size_t)34 * 130 * 64 * NS);

  warp_split_kernel<<<dim3(64, 20), 256, 0, stream>>>(xin, rec, ptm, act0);

  conv_kernel<256, 32, 64, 256, 1, 128, 32, 1, 0>
      <<<dim3(128, 1, 20), 256, 0, stream>>>(act0, w1s, b1, act1, (float*)nullptr);
  conv_kernel<32, 32, 64, 256, 1, 128, 32, 1, 0>
      <<<dim3(128, 1, 20), 256, 0, stream>>>(act1, w2s, b2, act2, (float*)nullptr);
  conv_kernel<32, 64, 64, 256, 2, 64, 64, 2, 0>
      <<<dim3(64, 1, 20), 256, 0, stream>>>(act2, w3s, b3, act3, (float*)nullptr);
  conv_kernel<64, 64, 32, 128, 1, 64, 64, 2, 0>
      <<<dim3(64, 1, 20), 256, 0, stream>>>(act3, w4s, b4, act4, (float*)nullptr);
  conv_kernel<64, 128, 32, 128, 2, 64, 64, 2, 1>
      <<<dim3(16, 2, 20), 256, 0, stream>>>(act4, w5s, b5, (_Float16*)nullptr, feat);

  mlp1a_kernel<20><<<dim3(512), 256, 0, stream>>>(feat, kw1, pk, 1);
  mlp1a_kernel<4><<<dim3(512), 256, 0, stream>>>(feat, qw1, pq, 5);
  mlp1b_kernel<<<dim3(24, 16), 256, 0, stream>>>(pk, pq, h1k, h1q);

  mlp2_kernel<<<dim3(24), 128, 0, stream>>>(
      h1k, h1q, kb1, kw2, kb2, kw3, kb3, qb1, qw2, qb2, qw3, qb3, keys, query);
  scores_kernel<<<dim3(1), 256, 0, stream>>>(keys, query, aw, ab, rec, attnb);
  fusion_kernel<<<dim3(64, 4, 4), 256, 0, stream>>>(xin, rec, ptm, attnb, out);
}